// Round 4
// baseline (539.530 us; speedup 1.0000x reference)
//
#include <hip/hip_runtime.h>
#include <stdint.h>
#include <math.h>

#define HH 512
#define WW 512
#define BB 32
#define CC 3
#define HWSZ (HH*WW)            // 262144
#define CHW (CC*HWSZ)           // 786432
#define NIMG (BB*CHW)           // 25165824
#define NMSK (BB*HWSZ)          // 8388608

// ---------------- Threefry-2x32 core ----------------
__host__ __device__ inline uint32_t rotl32(uint32_t x, uint32_t r){ return (x<<r)|(x>>(32u-r)); }

__host__ __device__ inline void tf2x32(uint32_t k0, uint32_t k1, uint32_t x0, uint32_t x1,
                                       uint32_t& o0, uint32_t& o1){
  uint32_t kx = k0 ^ k1 ^ 0x1BD11BDAu;
  uint32_t ks[3] = {k0, k1, kx};
  const uint32_t R[2][4] = {{13u,15u,26u,6u},{17u,29u,16u,24u}};
  x0 += ks[0]; x1 += ks[1];
  #pragma unroll
  for (int i = 0; i < 5; ++i){
    #pragma unroll
    for (int j = 0; j < 4; ++j){
      x0 += x1; x1 = rotl32(x1, R[i & 1][j]); x1 ^= x0;
    }
    x0 += ks[(i+1)%3];
    x1 += ks[(i+2)%3] + (uint32_t)(i+1);
  }
  o0 = x0; o1 = x1;
}

__host__ __device__ inline float bits_to_u01(uint32_t b){
  uint32_t fb = (b >> 9) | 0x3f800000u;
  float f;
#ifdef __HIP_DEVICE_COMPILE__
  f = __uint_as_float(fb);
#else
  union { uint32_t u; float f; } cv; cv.u = fb; f = cv.f;
#endif
  return f - 1.0f;
}

// XLA f32 ErfInv polynomial
__host__ __device__ inline float erfinv_f32(float x){
  float w = -log1pf(-x*x);
  float p;
  if (w < 5.0f){
    w -= 2.5f;
    p = 2.81022636e-08f;
    p = fmaf(p, w, 3.43273939e-07f);
    p = fmaf(p, w, -3.5233877e-06f);
    p = fmaf(p, w, -4.39150654e-06f);
    p = fmaf(p, w, 0.00021858087f);
    p = fmaf(p, w, -0.00125372503f);
    p = fmaf(p, w, -0.00417768164f);
    p = fmaf(p, w, 0.246640727f);
    p = fmaf(p, w, 1.50140941f);
  } else {
    w = sqrtf(w) - 3.0f;
    p = -0.000200214257f;
    p = fmaf(p, w, 0.000100950558f);
    p = fmaf(p, w, 0.00134934322f);
    p = fmaf(p, w, -0.00367342844f);
    p = fmaf(p, w, 0.00573950773f);
    p = fmaf(p, w, -0.0076224613f);
    p = fmaf(p, w, 0.00943887047f);
    p = fmaf(p, w, 1.00167406f);
    p = fmaf(p, w, 2.83297682f);
  }
  return p * x;
}

#define NRM_LO (-0.9999999403953552f)   /* nextafterf(-1,0) */
#define SQRT2F 1.41421356237309504880f

__host__ __device__ inline float normal_from_bits(uint32_t b){
  float f = bits_to_u01(b);
  float val = f * 2.0f + NRM_LO;    // (hi-lo) rounds to exactly 2.0f
  val = fmaxf(NRM_LO, val);
  return SQRT2F * erfinv_f32(val);
}

// ---------------- host-side jax.random (PARTITIONABLE threefry) ----------------
// split(key, n)[j]       = (o0, o1) of tf(key, 0, j)              [foldlike]
// random_bits(key,32)[i] = o0 XOR o1 of tf(key, hi(i), lo(i))     [counter mode, XOR!]
struct Key { uint32_t a, b; };

static Key foldSplit(Key k, uint32_t j){
  Key r; tf2x32(k.a, k.b, 0u, j, r.a, r.b); return r;
}

static uint32_t bits32(Key k, uint32_t i){
  uint32_t o0, o1; tf2x32(k.a, k.b, 0u, i, o0, o1); return o0 ^ o1;
}

static float unif_scalar(Key k){ return bits_to_u01(bits32(k, 0u)); }
static float normal_scalar(Key k){ return normal_from_bits(bits32(k, 0u)); }

// _gate: k1,k2 = split(key); randint(k1,(32,),0,2): (kh,kl) = split(k1),
// bern = bits(kl) & 1; u = uniform(k2,()); gate = bern*0.8 > u
static uint32_t gate_mask(Key kg){
  Key k1 = foldSplit(kg, 0u);
  Key k2 = foldSplit(kg, 1u);
  Key kl = foldSplit(k1, 1u);           // lower-bits key (second subkey)
  float u = bits_to_u01(bits32(k2, 0u));
  uint32_t m = 0;
  for (uint32_t i = 0; i < 32; ++i){
    float bern = (float)(bits32(kl, i) & 1u);
    if (bern * 0.8f > u) m |= (1u << i);
  }
  return m;
}

// ---------------- params ----------------
struct AugParams {
  uint32_t mFlip, mRot90, mTrans, mRot, mHue, mBri, mCon, mSat, mSharp, mNoise;
  float t, rotC, rotS, hShift, bri, con, sat, shp;
  uint32_t nk0, nk1;
};

// ---------------- device helpers ----------------
__device__ inline float clip01(float v){ return fminf(fmaxf(v, 0.0f), 1.0f); }

__device__ inline void permIdx(int y, int x, bool r9, bool fl, int& py, int& px){
  if (r9){ py = x; px = 511 - y; } else { py = y; px = x; }
  if (fl) px = 511 - px;
}

__device__ inline float tapP(const float* __restrict__ src, int y, int x, bool r9, bool fl){
  if ((unsigned)x >= 512u || (unsigned)y >= 512u) return 0.0f;
  int py, px; permIdx(y, x, r9, fl, py, px);
  return (src[py*512 + px] + 1.0f) * 0.5f;
}

// stage-1 (translate ∘ perm ∘ normalize), (ty,tx) in [0,512)
__device__ inline void stage1RGB(const float* __restrict__ base, int ty, int tx,
                                 bool r9, bool fl, bool tr, float t, float out[3]){
  if (!tr){
    #pragma unroll
    for (int c = 0; c < 3; ++c) out[c] = tapP(base + c*HWSZ, ty, tx, r9, fl);
    return;
  }
  float sx = (((float)tx - 255.5f) - t) + 255.5f;
  float sy = (((float)ty - 255.5f) - t) + 255.5f;
  float x0f = floorf(sx), y0f = floorf(sy);
  float wx = sx - x0f, wy = sy - y0f;
  int x0 = (int)x0f, y0 = (int)y0f;
  #pragma unroll
  for (int c = 0; c < 3; ++c){
    const float* s = base + c*HWSZ;
    float v00 = tapP(s, y0,   x0,   r9, fl);
    float v01 = tapP(s, y0,   x0+1, r9, fl);
    float v10 = tapP(s, y0+1, x0,   r9, fl);
    float v11 = tapP(s, y0+1, x0+1, r9, fl);
    float top = v00*(1.0f-wx) + v01*wx;
    float bot = v10*(1.0f-wx) + v11*wx;
    out[c] = top*(1.0f-wy) + bot*wy;
  }
}

__device__ inline void rotTap(const float* __restrict__ base, int ty, int tx,
                              bool r9, bool fl, bool tr, float t, float o[3]){
  if ((unsigned)tx < 512u && (unsigned)ty < 512u){
    stage1RGB(base, ty, tx, r9, fl, tr, t, o);
  } else {
    o[0] = o[1] = o[2] = 0.0f;
  }
}

__device__ inline void rgb2hsv(float r, float g, float b, float& h, float& s, float& v){
  float maxc = fmaxf(fmaxf(r, g), b);
  float minc = fminf(fminf(r, g), b);
  float cr = maxc - minc;
  s = cr / ((maxc == 0.0f) ? 1.0f : maxc);
  float crd = (cr == 0.0f) ? 1.0f : cr;
  float rc = (maxc - r) / crd;
  float gc = (maxc - g) / crd;
  float bc = (maxc - b) / crd;
  float hh;
  if (maxc == r)      hh = bc - gc;
  else if (maxc == g) hh = 2.0f + rc - bc;
  else                hh = 4.0f + gc - rc;
  if (cr == 0.0f) hh = 0.0f;
  else { hh = hh / 6.0f; hh = hh - floorf(hh); }
  h = hh; v = maxc;
}

__device__ inline void hsv2rgb(float h, float s, float v, float& r, float& g, float& b){
  float i = floorf(h * 6.0f);
  float f = h * 6.0f - i;
  float p = v * (1.0f - s);
  float q = v * (1.0f - f * s);
  float t = v * (1.0f - (1.0f - f) * s);
  int ii = ((int)i) % 6;
  switch (ii){
    case 0: r = v; g = t; b = p; break;
    case 1: r = q; g = v; b = p; break;
    case 2: r = p; g = v; b = t; break;
    case 3: r = p; g = q; b = v; break;
    case 4: r = t; g = p; b = v; break;
    default: r = v; g = p; b = q; break;
  }
}

// stage-2: perm+translate+rotate+hue+brightness, straight from d_in
__device__ inline void stage2RGB(const float* __restrict__ base, int yy, int xx,
                                 const AugParams& P, int b, float v[3]){
  bool fl  = (P.mFlip  >> b) & 1u;
  bool r9  = (P.mRot90 >> b) & 1u;
  bool tr  = (P.mTrans >> b) & 1u;
  bool rot = (P.mRot   >> b) & 1u;
  bool hue = (P.mHue   >> b) & 1u;
  bool bri = (P.mBri   >> b) & 1u;
  if (rot){
    float dx = (float)xx - 255.5f;
    float dy = (float)yy - 255.5f;
    float sx = (P.rotC*dx + P.rotS*dy) + 255.5f;
    float sy = (-P.rotS*dx + P.rotC*dy) + 255.5f;
    float x0f = floorf(sx), y0f = floorf(sy);
    float wx = sx - x0f, wy = sy - y0f;
    int x0 = (int)x0f, y0 = (int)y0f;
    float q00[3], q01[3], q10[3], q11[3];
    rotTap(base, y0,   x0,   r9, fl, tr, P.t, q00);
    rotTap(base, y0,   x0+1, r9, fl, tr, P.t, q01);
    rotTap(base, y0+1, x0,   r9, fl, tr, P.t, q10);
    rotTap(base, y0+1, x0+1, r9, fl, tr, P.t, q11);
    #pragma unroll
    for (int c = 0; c < 3; ++c){
      float top = q00[c]*(1.0f-wx) + q01[c]*wx;
      float bot = q10[c]*(1.0f-wx) + q11[c]*wx;
      v[c] = top*(1.0f-wy) + bot*wy;
    }
  } else {
    stage1RGB(base, yy, xx, r9, fl, tr, P.t, v);
  }
  if (hue){
    float r = clip01(v[0]), g = clip01(v[1]), bb = clip01(v[2]);
    float h, s, val;
    rgb2hsv(r, g, bb, h, s, val);
    h = h + P.hShift;
    h = h - floorf(h);
    hsv2rgb(h, s, val, v[0], v[1], v[2]);
  }
  if (bri){
    #pragma unroll
    for (int c = 0; c < 3; ++c) v[c] = clip01(v[c] * P.bri);
  }
}

__device__ inline void procCS(float v[3], bool con, float cmul, float cadd, bool sat, float smul){
  if (con){
    #pragma unroll
    for (int c = 0; c < 3; ++c) v[c] = clip01(cmul * v[c] + cadd);
  }
  if (sat){
    float g = 0.2989f*v[0] + 0.587f*v[1] + 0.114f*v[2];
    float gadd = (1.0f - smul) * g;
    #pragma unroll
    for (int c = 0; c < 3; ++c) v[c] = clip01(smul * v[c] + gadd);
  }
}

// ---------------- kernels ----------------

__global__ void kZero(float* meanAcc){
  int t = threadIdx.x;
  if (t < 32) meanAcc[t] = 0.0f;
}

// Mask: permutation + nearest rotation (translation provably identity for nearest).
__global__ __launch_bounds__(256) void kMask(const float* __restrict__ msk,
                                             float* __restrict__ out, AugParams P){
  int x = blockIdx.x*blockDim.x + threadIdx.x;
  int y = blockIdx.y*blockDim.y + threadIdx.y;
  int b = blockIdx.z;
  bool fl  = (P.mFlip  >> b) & 1u;
  bool r9  = (P.mRot90 >> b) & 1u;
  bool rot = (P.mRot   >> b) & 1u;
  float v;
  if (rot){
    float dx = __fsub_rn((float)x, 255.5f);
    float dy = __fsub_rn((float)y, 255.5f);
    float sx = __fadd_rn(__fadd_rn(__fmul_rn(P.rotC, dx), __fmul_rn(P.rotS, dy)), 255.5f);
    float sy = __fadd_rn(__fadd_rn(__fmul_rn(-P.rotS, dx), __fmul_rn(P.rotC, dy)), 255.5f);
    float xi = rintf(sx), yi = rintf(sy);
    bool valid = (xi >= 0.0f) && (xi < 512.0f) && (yi >= 0.0f) && (yi < 512.0f);
    int xc = (int)fminf(fmaxf(xi, 0.0f), 511.0f);
    int yc = (int)fminf(fmaxf(yi, 0.0f), 511.0f);
    int py, px; permIdx(yc, xc, r9, fl, py, px);
    v = valid ? msk[(size_t)b*HWSZ + py*512 + px] : 0.0f;
  } else {
    int py, px; permIdx(y, x, r9, fl, py, px);
    v = msk[(size_t)b*HWSZ + py*512 + px];
  }
  out[(size_t)b*HWSZ + y*512 + x] = v;
}

// Contrast mean: recompute stage-2 gray, block-reduce, atomicAdd.
__global__ __launch_bounds__(256) void kMean(const float* __restrict__ img,
                                             float* __restrict__ meanAcc, AugParams P){
  int b = blockIdx.z;
  if (!((P.mCon >> b) & 1u)) return;
  int x = blockIdx.x*blockDim.x + threadIdx.x;
  int y = blockIdx.y*blockDim.y + threadIdx.y;
  float v[3];
  stage2RGB(img + (size_t)b*CHW, y, x, P, b, v);
  float gray = 0.2989f*v[0] + 0.587f*v[1] + 0.114f*v[2];
  __shared__ float sred[256];
  int tid = threadIdx.y*blockDim.x + threadIdx.x;
  sred[tid] = gray;
  __syncthreads();
  for (int s = 128; s > 0; s >>= 1){
    if (tid < s) sred[tid] += sred[tid + s];
    __syncthreads();
  }
  if (tid == 0) atomicAdd(&meanAcc[b], sred[0]);
}

// Final: one batch per block-z. stage-2 + contrast/sat -> LDS (1px halo),
// sharpness from LDS, partitionable-threefry noise (XOR of both words), renorm, write.
__global__ __launch_bounds__(256) void kFinal(const float* __restrict__ img,
                                              const float* __restrict__ meanAcc,
                                              float* __restrict__ out, AugParams P){
  __shared__ float s2[10][34][3];
  int tx = threadIdx.x, ty = threadIdx.y;
  int tid = ty*32 + tx;
  int bx = blockIdx.x, by = blockIdx.y, b = blockIdx.z;
  const float W1 = 1.0f/13.0f, W5 = 5.0f/13.0f;

  bool con = (P.mCon   >> b) & 1u;
  bool sat = (P.mSat   >> b) & 1u;
  bool shg = (P.mSharp >> b) & 1u;
  bool noi = (P.mNoise >> b) & 1u;
  float mean = meanAcc[b] * (1.0f/262144.0f);
  float cadd = (1.0f - P.con) * mean;
  const float* base = img + (size_t)b*CHW;

  for (int cell = tid; cell < 340; cell += 256){
    int r = cell / 34, cc = cell % 34;
    int gy = by*8 + r - 1, gx = bx*32 + cc - 1;
    float v[3] = {0.0f, 0.0f, 0.0f};
    if ((unsigned)gx < 512u && (unsigned)gy < 512u){
      stage2RGB(base, gy, gx, P, b, v);
      procCS(v, con, P.con, cadd, sat, P.sat);
    }
    s2[r][cc][0] = v[0]; s2[r][cc][1] = v[1]; s2[r][cc][2] = v[2];
  }
  __syncthreads();

  int x = bx*32 + tx, y = by*8 + ty;
  bool interior = (x >= 1) && (x <= 510) && (y >= 1) && (y <= 510);
  float res[3];
  float c0[3] = { s2[ty+1][tx+1][0], s2[ty+1][tx+1][1], s2[ty+1][tx+1][2] };
  if (shg && interior){
    float nsum[3] = {0.0f, 0.0f, 0.0f};
    #pragma unroll
    for (int dy = 0; dy < 3; ++dy){
      #pragma unroll
      for (int dxx = 0; dxx < 3; ++dxx){
        if (dxx == 1 && dy == 1) continue;
        #pragma unroll
        for (int c = 0; c < 3; ++c) nsum[c] += s2[ty+dy][tx+dxx][c];
      }
    }
    #pragma unroll
    for (int c = 0; c < 3; ++c){
      float bl = clip01(nsum[c]*W1 + c0[c]*W5);
      res[c] = clip01(P.shp * c0[c] + (1.0f - P.shp) * bl);
    }
  } else {
    res[0] = c0[0]; res[1] = c0[1]; res[2] = c0[2];
  }

  if (noi){
    #pragma unroll
    for (int c = 0; c < 3; ++c){
      uint32_t idx = (uint32_t)(b*CHW + c*HWSZ + y*512 + x);
      uint32_t o0, o1;
      tf2x32(P.nk0, P.nk1, 0u, idx, o0, o1);
      res[c] += normal_from_bits(o0 ^ o1) * 0.1f;   // partitionable: XOR both words
    }
  }
  #pragma unroll
  for (int c = 0; c < 3; ++c){
    out[(size_t)b*CHW + (size_t)c*HWSZ + y*512 + x] = (res[c] - 0.5f) * 2.0f;
  }
}

// ---------------- launch ----------------
extern "C" void kernel_launch(void* const* d_in, const int* in_sizes, int n_in,
                              void* d_out, int out_size, void* d_ws, size_t ws_size,
                              hipStream_t stream) {
  const float* images = (const float*)d_in[0];
  const float* masks  = (const float*)d_in[1];
  float* out_img = (float*)d_out;
  float* out_msk = out_img + (size_t)NIMG;
  float* meanAcc = (float*)d_ws;   // 32 floats

  Key root; root.a = 0u; root.b = 42u;
  Key ks[18];
  for (uint32_t j = 0; j < 18; ++j) ks[j] = foldSplit(root, j);

  AugParams P;
  P.mFlip  = gate_mask(ks[0]);
  P.mRot90 = gate_mask(ks[1]);
  P.mTrans = gate_mask(ks[2]);
  P.t      = unif_scalar(ks[3]) * 0.125f;
  P.mRot   = gate_mask(ks[4]);
  float r  = unif_scalar(ks[5]) * 10.0f;
  P.mHue   = gate_mask(ks[6]);
  P.hShift = (unif_scalar(ks[7]) - 0.5f) * 0.95f;
  P.mBri   = gate_mask(ks[8]);
  P.bri    = fabsf(1.0f + normal_scalar(ks[9])  * 0.2f);
  P.mCon   = gate_mask(ks[10]);
  P.con    = fabsf(1.0f + normal_scalar(ks[11]) * 0.2f);
  P.mSat   = gate_mask(ks[12]);
  P.sat    = fabsf(1.0f + normal_scalar(ks[13]) * 0.2f);
  P.mSharp = gate_mask(ks[14]);
  P.shp    = fabsf(1.0f + normal_scalar(ks[15]) * 1.0f);
  P.mNoise = gate_mask(ks[16]);
  P.nk0 = ks[17].a; P.nk1 = ks[17].b;

  float th = r * 0.017453292519943295f;   // single f32 multiply (match XLA deg2rad)
  P.rotC = (float)cos((double)th);
  P.rotS = (float)sin((double)th);

  dim3 blk(32, 8, 1);
  kZero<<<1, 64, 0, stream>>>(meanAcc);
  kMask<<<dim3(16, 64, 32), blk, 0, stream>>>(masks, out_msk, P);
  kMean<<<dim3(16, 64, 32), blk, 0, stream>>>(images, meanAcc, P);
  kFinal<<<dim3(16, 64, 32), blk, 0, stream>>>(images, meanAcc, out_img, P);
}